// Round 7
// baseline (674.200 us; speedup 1.0000x reference)
//
#include <hip/hip_runtime.h>

#define Bb 32
#define Tt 64
#define Nn 300
#define Dd 128
#define NC (Nn * Dd)              // 38400 columns per (b,t) row
#define BTND ((size_t)Tt * NC)    // 2457600 elems per batch

// Kernel 1: fused  Q[bt,n] = sum_d src*wt1   (kept in LDS only)
//                  K[bt,d] = sum_n wt3*src
//                  QW[bt,d] = sum_n Q[bt,n]*wt2[n,d]
// One block per bt; 8 half-wave groups; group g does row n0+g, lane covers
// 4 consecutive d (float4). HBM floor: 1.26 GB src read ~200 us.
// Round-7 change: QW phase uses ALL 256 threads (n-range split across the
// two 128-thread halves, LDS partials, pairwise reduce) instead of idling
// half the block through a 75-iteration serial loop.
__global__ __launch_bounds__(256) void qkw_kernel(
        const float* __restrict__ src, const float* __restrict__ wt1,
        const float* __restrict__ wt2, const float* __restrict__ wt3,
        float* __restrict__ QW, float* __restrict__ K) {
    __shared__ float wt3_s[Nn];
    __shared__ float qs[Nn];        // Q row, consumed in-block by QW phase
    __shared__ float kred[8 * Dd];  // 8 groups x 128 d = 4 KB
    __shared__ float qwp[2 * Dd];   // QW partials (two halves) = 1 KB
    const int tid = threadIdx.x;
    const int grp = tid >> 5;       // 0..7
    const int gl = tid & 31;        // lane within group
    for (int i = tid; i < Nn; i += 256) wt3_s[i] = wt3[i];
    __syncthreads();
    const int d0 = gl * 4;
    const float4 w1 = *(const float4*)(wt1 + d0);
    const float* sbt = src + (size_t)blockIdx.x * NC;
    float4 k = {0.f, 0.f, 0.f, 0.f};
    for (int n0 = 0; n0 < Nn; n0 += 8) {
        const int n = n0 + grp;
        if (n < Nn) {  // 300 = 8*37+4: groups 4..7 idle on the last iter
            float4 v = *(const float4*)(sbt + n * Dd + d0);
            float q = v.x * w1.x + v.y * w1.y + v.z * w1.z + v.w * w1.w;
            #pragma unroll
            for (int off = 16; off > 0; off >>= 1) q += __shfl_down(q, off, 32);
            if (gl == 0) qs[n] = q;
            const float w3 = wt3_s[n];
            k.x = fmaf(w3, v.x, k.x);
            k.y = fmaf(w3, v.y, k.y);
            k.z = fmaf(w3, v.z, k.z);
            k.w = fmaf(w3, v.w, k.w);
        }
    }
    *(float4*)(kred + grp * Dd + d0) = k;
    __syncthreads();
    // K final reduce on threads 0..127 (reads kred; qwp is a separate
    // buffer so the QW partial writes below cannot race these reads).
    if (tid < Dd) {
        float s = 0.f;
        #pragma unroll
        for (int g = 0; g < 8; ++g) s += kred[g * Dd + tid];
        K[(size_t)blockIdx.x * Dd + tid] = s;
    }
    // QW partials: all 256 threads. half h covers n in [150h, 150h+150);
    // wt2 reads coalesce (thread d -> wt2[n*128+d], 512 B per half-wave).
    {
        const int d = tid & 127, half = tid >> 7;
        const float* w2c = wt2 + d;
        float qw0 = 0.f, qw1 = 0.f;
        const int nb = 150 * half;
        for (int n = nb; n < nb + 150; n += 2) {  // 150 = 2*75 exact
            qw0 = fmaf(qs[n], w2c[(size_t)n * Dd], qw0);
            qw1 = fmaf(qs[n + 1], w2c[(size_t)(n + 1) * Dd], qw1);
        }
        qwp[half * Dd + d] = qw0 + qw1;
    }
    __syncthreads();
    if (tid < Dd)
        QW[(size_t)blockIdx.x * Dd + tid] = qwp[tid] + qwp[Dd + tid];
}

// Kernel 2: fused scores + batch-softmax. Block = (k, q) via dim3(64,64);
// 128 thr = 4 groups x 32 lanes; group bg handles b = 8*bg..8*bg+7.
// All QW/K loads are coalesced float4 (the uncoalesced K-read of the old
// score kernel is gone). Softmax over b in-block; writes att + I.
__global__ __launch_bounds__(128) void score_softmax_kernel(
        const float* __restrict__ QW, const float* __restrict__ K,
        float* __restrict__ att) {
    __shared__ float sc[Bb];
    const int kk = blockIdx.x, q = blockIdx.y;
    const int tid = threadIdx.x;
    const int bg = tid >> 5, gl = tid & 31;
    const int d0 = gl * 4;
    #pragma unroll
    for (int i = 0; i < 8; ++i) {
        const int b = bg * 8 + i;
        const float4 qw = *(const float4*)(QW + ((size_t)b * Tt + q) * Dd + d0);
        const float4 kv = *(const float4*)(K + ((size_t)b * Tt + kk) * Dd + d0);
        float p = qw.x * kv.x + qw.y * kv.y + qw.z * kv.z + qw.w * kv.w;
        #pragma unroll
        for (int off = 16; off > 0; off >>= 1) p += __shfl_down(p, off, 32);
        if (gl == 0) sc[b] = p;
    }
    __syncthreads();
    float m = -1e30f;
    #pragma unroll
    for (int b = 0; b < Bb; ++b) m = fmaxf(m, sc[b]);  // LDS broadcast, uniform
    float sum = 0.f;
    #pragma unroll
    for (int b = 0; b < Bb; ++b) sum += __expf(sc[b] - m);
    if (tid < Bb) {
        const float diag = (q == kk) ? 1.0f : 0.0f;
        att[(size_t)tid * (Tt * Tt) + q * Tt + kk] =
            __expf(sc[tid] - m) / sum + diag;
    }
}

// Kernel 3: out[b,a,j] = sum_t attI[b,t,a] * src[b,t,j]  (attI = att + I).
// acc[8][4] (32 regs), (512,6) -> 3 blocks/CU. Round-7 change: REVERSED
// block->(b, j-chunk) map. qkw streams src in ascending bt order, so when
// mix launches, the LAST ~256 MB of src (b~26..31) is L3-resident; mix's
// first-dispatched blocks now start there instead of at cold b=0 —
// harvesting up to ~250 MB of L3 hits on the second src pass.
//   round-1: (512,2) -> 1 block/CU -> latency-bound.
//   round-2: (512,6) + 64 acc -> spill (32 acc has 2x margin).
//   round-3: per-iter uniform s_load att reads serialize.
#define MIX_JT 256  // j floats per block: 64 lanes * 4
__global__ __launch_bounds__(512, 6) void mix_kernel(
        const float* __restrict__ src, const float* __restrict__ attI,
        float* __restrict__ out) {
    __shared__ float att_s[Tt * Tt];  // [t][a], 16 KB
    const int tid = threadIdx.x;
    const int b = (Bb - 1) - blockIdx.y;            // reversed: warm tail first
    const int jc = (NC / MIX_JT - 1) - blockIdx.x;  // reversed within batch
    for (int i = tid; i < Tt * Tt; i += 512)
        att_s[i] = attI[(size_t)b * Tt * Tt + i];
    __syncthreads();
    const int wave = tid >> 6, lane = tid & 63;
    const int a0 = wave * 8;
    const int j = jc * MIX_JT + lane * 4;
    const float* sb = src + (size_t)b * BTND + j;
    float* ob = out + (size_t)b * BTND + j;
    float acc[8][4];
    #pragma unroll
    for (int ai = 0; ai < 8; ++ai)
        #pragma unroll
        for (int jj = 0; jj < 4; ++jj) acc[ai][jj] = 0.f;
    float4 x = *(const float4*)sb;
    for (int t = 0; t < Tt; ++t) {
        const int tn = (t < Tt - 1) ? t + 1 : t;
        const float4 xn = *(const float4*)(sb + (size_t)tn * NC);
        const float4 av0 = *(const float4*)(att_s + t * Tt + a0);
        const float4 av1 = *(const float4*)(att_s + t * Tt + a0 + 4);
        const float av[8] = {av0.x, av0.y, av0.z, av0.w,
                             av1.x, av1.y, av1.z, av1.w};
        #pragma unroll
        for (int ai = 0; ai < 8; ++ai) {
            acc[ai][0] = fmaf(av[ai], x.x, acc[ai][0]);
            acc[ai][1] = fmaf(av[ai], x.y, acc[ai][1]);
            acc[ai][2] = fmaf(av[ai], x.z, acc[ai][2]);
            acc[ai][3] = fmaf(av[ai], x.w, acc[ai][3]);
        }
        x = xn;
    }
    #pragma unroll
    for (int ai = 0; ai < 8; ++ai) {
        float4 s = {acc[ai][0], acc[ai][1], acc[ai][2], acc[ai][3]};
        *(float4*)(ob + (size_t)(a0 + ai) * NC) = s;
    }
}

extern "C" void kernel_launch(void* const* d_in, const int* in_sizes, int n_in,
                              void* d_out, int out_size, void* d_ws, size_t ws_size,
                              hipStream_t stream) {
    const float* src = (const float*)d_in[0];
    const float* wt1 = (const float*)d_in[1];
    const float* wt2 = (const float*)d_in[2];
    const float* wt3 = (const float*)d_in[3];
    float* out = (float*)d_out;

    float* ws = (float*)d_ws;
    float* QW  = ws;                               // B*T*D = 262144 floats
    float* K   = QW + (size_t)Bb * Tt * Dd;        // B*T*D = 262144 floats
    float* att = K + (size_t)Bb * Tt * Dd;         // B*T*T = 131072 floats
    // total ws use: ~2.6 MB

    qkw_kernel<<<Bb * Tt, 256, 0, stream>>>(src, wt1, wt2, wt3, QW, K);
    dim3 g2(Tt, Tt);
    score_softmax_kernel<<<g2, 128, 0, stream>>>(QW, K, att);
    dim3 g3(NC / MIX_JT, Bb);
    mix_kernel<<<g3, 512, 0, stream>>>(src, att, out);
}